// Round 1
// baseline (266.116 us; speedup 1.0000x reference)
//
#include <hip/hip_runtime.h>
#include <math.h>

#define K1 17
#define SEG_F (K1 * 256)          // 4352 floats per segment-array
#define PART_F (2 * SEG_F + 32)   // 8736 floats per block partial region

// ---------------- Pass 1: per-block segment partial sums ----------------
__global__ __launch_bounds__(512) void k1_partials(
    const float4* __restrict__ dp, const float4* __restrict__ cf,
    const int* __restrict__ mask, float* __restrict__ part,
    int nPart, int nRows)
{
    __shared__ float s[2 * SEG_F];
    __shared__ float scnt[K1];
    const int tid = threadIdx.x;
    for (int i = tid; i < 2 * SEG_F; i += 512) s[i] = 0.0f;
    if (tid < K1) scnt[tid] = 0.0f;
    __syncthreads();

    const int lane = tid & 63;
    const int gw = blockIdx.x * 8 + (tid >> 6);
    const int S = nPart * 8;

    int r = gw;
    for (; r + 3 * S < nRows; r += 4 * S) {
        int lb[4]; float4 vv[4], ww[4];
        #pragma unroll
        for (int u = 0; u < 4; ++u) {
            const int rr = r + u * S;
            lb[u] = mask[rr];
            vv[u] = dp[rr * 64 + lane];
            ww[u] = cf[rr * 64 + lane];
        }
        #pragma unroll
        for (int u = 0; u < 4; ++u) {
            const float4 v = vv[u], w = ww[u];
            float ssd = v.x * v.x + v.y * v.y + v.z * v.z + v.w * v.w;
            float ssc = w.x * w.x + w.y * w.y + w.z * w.z + w.w * w.w;
            #pragma unroll
            for (int o = 32; o > 0; o >>= 1) {
                ssd += __shfl_xor(ssd, o, 64);
                ssc += __shfl_xor(ssc, o, 64);
            }
            const float invd = 1.0f / fmaxf(sqrtf(ssd), 1e-12f);
            const float invc = 1.0f / fmaxf(sqrtf(ssc), 1e-12f);
            // permuted layout: element d=lane*4+j stored at j*64+lane -> bank lane%32 (2-way, free)
            float* sd = s + lb[u] * 256 + lane;
            float* sc = sd + SEG_F;
            atomicAdd(sd,       v.x * invd);
            atomicAdd(sd + 64,  v.y * invd);
            atomicAdd(sd + 128, v.z * invd);
            atomicAdd(sd + 192, v.w * invd);
            atomicAdd(sc,       w.x * invc);
            atomicAdd(sc + 64,  w.y * invc);
            atomicAdd(sc + 128, w.z * invc);
            atomicAdd(sc + 192, w.w * invc);
            if (lane == 0) atomicAdd(&scnt[lb[u]], 1.0f);
        }
    }
    for (; r < nRows; r += S) {
        const int label = mask[r];
        const float4 v = dp[r * 64 + lane];
        const float4 w = cf[r * 64 + lane];
        float ssd = v.x * v.x + v.y * v.y + v.z * v.z + v.w * v.w;
        float ssc = w.x * w.x + w.y * w.y + w.z * w.z + w.w * w.w;
        #pragma unroll
        for (int o = 32; o > 0; o >>= 1) {
            ssd += __shfl_xor(ssd, o, 64);
            ssc += __shfl_xor(ssc, o, 64);
        }
        const float invd = 1.0f / fmaxf(sqrtf(ssd), 1e-12f);
        const float invc = 1.0f / fmaxf(sqrtf(ssc), 1e-12f);
        float* sd = s + label * 256 + lane;
        float* sc = sd + SEG_F;
        atomicAdd(sd,       v.x * invd);
        atomicAdd(sd + 64,  v.y * invd);
        atomicAdd(sd + 128, v.z * invd);
        atomicAdd(sd + 192, v.w * invd);
        atomicAdd(sc,       w.x * invc);
        atomicAdd(sc + 64,  w.y * invc);
        atomicAdd(sc + 128, w.z * invc);
        atomicAdd(sc + 192, w.w * invc);
        if (lane == 0) atomicAdd(&scnt[label], 1.0f);
    }
    __syncthreads();
    float* outp = part + (size_t)blockIdx.x * PART_F;
    for (int i = tid; i < 2 * SEG_F; i += 512) outp[i] = s[i];
    if (tid < K1) outp[2 * SEG_F + tid] = scnt[tid];
}

// ------------- Reduce partials -> mu_dp, mu_cf, cnt; zero loss accs -------------
__global__ __launch_bounds__(1024) void k2_mu(float* __restrict__ ws, int nPart, int muBase)
{
    const int k = blockIdx.x;   // segment 0..16
    const int t = threadIdx.x;  // 0..1023
    const int p = t & 255;      // permuted element index
    const int bs = t >> 8;      // 0..3

    float sd = 0.0f, sc = 0.0f;
    for (int b = bs; b < nPart; b += 4) {
        const float* reg = ws + (size_t)b * PART_F;
        sd += reg[k * 256 + p];
        sc += reg[SEG_F + k * 256 + p];
    }
    __shared__ float A[1024], B[1024], Cc[256];
    A[t] = sd; B[t] = sc;
    __syncthreads();

    float td = 0.0f, tc = 0.0f;
    if (t < 256) {
        td = A[t] + A[t + 256] + A[t + 512] + A[t + 768];
        tc = B[t] + B[t + 256] + B[t + 512] + B[t + 768];
        Cc[t] = (t < nPart) ? ws[(size_t)t * PART_F + 2 * SEG_F + k] : 0.0f;
    }
    __syncthreads();
    for (int s2 = 128; s2 > 0; s2 >>= 1) {
        if (t < s2) Cc[t] += Cc[t + s2];
        __syncthreads();
    }
    const float cnt  = Cc[0];
    const float safe = fmaxf(cnt, 1.0f);
    const float md = td / safe, mc = tc / safe;
    __syncthreads();
    if (t < 256) { A[t] = md * md; B[t] = mc * mc; }
    __syncthreads();
    for (int s2 = 128; s2 > 0; s2 >>= 1) {
        if (t < s2) { A[t] += A[t + s2]; B[t] += B[t + s2]; }
        __syncthreads();
    }
    const float invd = 1.0f / fmaxf(sqrtf(A[0]), 1e-12f);
    const float invc = 1.0f / fmaxf(sqrtf(B[0]), 1e-12f);
    if (t < 256) {
        ws[muBase + k * 256 + t]         = md * invd;   // mu_dp (permuted layout)
        ws[muBase + SEG_F + k * 256 + t] = mc * invc;   // mu_cf
    }
    if (t == 0) {
        ws[muBase + 2 * SEG_F + k] = cnt;
        ws[muBase + 2 * SEG_F + K1 + k] = 0.0f;       // loss_t accumulator
        ws[muBase + 2 * SEG_F + 2 * K1 + k] = 0.0f;   // loss_cf accumulator
    }
}

// ---------------- Pass 2: per-pixel losses -> per-segment sums ----------------
__global__ __launch_bounds__(512) void k3_loss(
    const float4* __restrict__ dp, const float4* __restrict__ cf,
    const int* __restrict__ mask, float* __restrict__ ws,
    int muBase, int nBlocks, int nRows)
{
    __shared__ float mud[SEG_F], muc[SEG_F];
    __shared__ float lt[K1], lc[K1];
    const int tid = threadIdx.x;
    for (int i = tid; i < SEG_F; i += 512) {
        mud[i] = ws[muBase + i];
        muc[i] = ws[muBase + SEG_F + i];
    }
    if (tid < K1) { lt[tid] = 0.0f; lc[tid] = 0.0f; }
    __syncthreads();

    const int lane = tid & 63;
    const int gw = blockIdx.x * 8 + (tid >> 6);
    const int S = nBlocks * 8;

    for (int r = gw; r < nRows; r += S) {
        const int label = mask[r];
        const float4 v = dp[r * 64 + lane];
        const float4 w = cf[r * 64 + lane];
        float ssd = v.x * v.x + v.y * v.y + v.z * v.z + v.w * v.w;
        float ssc = w.x * w.x + w.y * w.y + w.z * w.z + w.w * w.w;
        const float* md_ = mud + label * 256 + lane;
        const float* mb_ = mud + lane;           // segment 0 (background)
        const float* mc_ = muc + label * 256 + lane;
        const float* cb_ = muc + lane;
        float dmu = v.x * md_[0] + v.y * md_[64] + v.z * md_[128] + v.w * md_[192];
        float dbg = v.x * mb_[0] + v.y * mb_[64] + v.z * mb_[128] + v.w * mb_[192];
        float cmu = w.x * mc_[0] + w.y * mc_[64] + w.z * mc_[128] + w.w * mc_[192];
        float cbg = w.x * cb_[0] + w.y * cb_[64] + w.z * cb_[128] + w.w * cb_[192];
        #pragma unroll
        for (int o = 32; o > 0; o >>= 1) {
            ssd += __shfl_xor(ssd, o, 64);
            ssc += __shfl_xor(ssc, o, 64);
            dmu += __shfl_xor(dmu, o, 64);
            dbg += __shfl_xor(dbg, o, 64);
            cmu += __shfl_xor(cmu, o, 64);
            cbg += __shfl_xor(cbg, o, 64);
        }
        if (lane == 0) {
            const float invd = 1.0f / fmaxf(sqrtf(ssd), 1e-12f);
            const float invc = 1.0f / fmaxf(sqrtf(ssc), 1e-12f);
            const float xt = (dbg - dmu) * invd * (1.0f / 0.07f);
            const float xc = (cmu - cbg) * invc * (1.0f / 0.07f);
            const float plt = fmaxf(xt, 0.0f) + log1pf(expf(-fabsf(xt)));
            const float plc = fmaxf(xc, 0.0f) + log1pf(expf(-fabsf(xc)));
            atomicAdd(&lt[label], plt);
            atomicAdd(&lc[label], plc);
        }
    }
    __syncthreads();
    if (tid < K1) {
        atomicAdd(&ws[muBase + 2 * SEG_F + K1 + tid], lt[tid]);
        atomicAdd(&ws[muBase + 2 * SEG_F + 2 * K1 + tid], lc[tid]);
    }
}

// ---------------- Finalize scalar loss ----------------
__global__ void k4_final(const float* __restrict__ ws, float* __restrict__ out, int muBase)
{
    const int t = threadIdx.x; // 64 threads
    float vt = 0.0f, vc = 0.0f, nv = 0.0f;
    if (t >= 1 && t < K1) {
        const float cnt = ws[muBase + 2 * SEG_F + t];
        if (cnt >= 3.0f) {  // MIN_PIXELS
            const float safe = fmaxf(cnt, 1.0f);
            vt = ws[muBase + 2 * SEG_F + K1 + t] / safe;
            vc = ws[muBase + 2 * SEG_F + 2 * K1 + t] / safe;
            nv = 1.0f;
        }
    }
    #pragma unroll
    for (int o = 32; o > 0; o >>= 1) {
        vt += __shfl_xor(vt, o, 64);
        vc += __shfl_xor(vc, o, 64);
        nv += __shfl_xor(nv, o, 64);
    }
    if (t == 0) {
        const float n = fmaxf(nv, 1.0f);
        out[0] = vt / n + 0.5f * (vc / n);  // LAMBDA_CF = 0.5
    }
}

extern "C" void kernel_launch(void* const* d_in, const int* in_sizes, int n_in,
                              void* d_out, int out_size, void* d_ws, size_t ws_size,
                              hipStream_t stream)
{
    const float4* dp  = (const float4*)d_in[0];
    const float4* cf  = (const float4*)d_in[1];
    const int* mask   = (const int*)d_in[2];
    float* ws  = (float*)d_ws;
    float* out = (float*)d_out;
    const int nRows = in_sizes[2];

    // sizing: nPart block-partial regions + mu/cnt/loss tail
    const long tailF = 2 * SEG_F + 3 * K1 + 64;
    long availF = (long)(ws_size / 4) - tailF;
    int nPart = (int)(availF / PART_F);
    if (nPart > 256) nPart = 256;
    if (nPart < 1) nPart = 1;
    const int muBase = nPart * PART_F;

    k1_partials<<<nPart, 512, 0, stream>>>(dp, cf, mask, ws, nPart, nRows);
    k2_mu<<<K1, 1024, 0, stream>>>(ws, nPart, muBase);
    const int nB3 = 512;
    k3_loss<<<nB3, 512, 0, stream>>>(dp, cf, mask, ws, muBase, nB3, nRows);
    k4_final<<<1, 64, 0, stream>>>(ws, out, muBase);
}